// Round 5
// baseline (1281.820 us; speedup 1.0000x reference)
//
#include <hip/hip_runtime.h>
#include <stdint.h>

typedef __attribute__((ext_vector_type(8))) short short8;
typedef __attribute__((ext_vector_type(4))) float floatx4;

#define P_TOT (16 * 256 * 256)
#define P_IMG 65536

__device__ __forceinline__ unsigned short f2bf(float f) {
    unsigned int u = __float_as_uint(f);
    return (unsigned short)((u + 0x7FFFu + ((u >> 16) & 1u)) >> 16);
}
__device__ __forceinline__ float bf2f(unsigned short h) {
    return __uint_as_float(((unsigned int)h) << 16);
}

// ---- repack OIHW fp32 weights -> bf16 MFMA B-fragment order -----------------
__global__ void repack_w(const float* __restrict__ w, unsigned short* __restrict__ bp,
                         int ngroups, int creal) {
    int idx = blockIdx.x * 256 + threadIdx.x;
    if (idx >= ngroups * 9216) return;
    int j = idx & 7;
    int lane = (idx >> 3) & 63;
    int gt = idx >> 9;            // g*18 + t
    int t = gt % 18;
    int n = (gt / 18) * 16 + (lane & 15);
    int tap = t >> 1, hf = t & 1;
    int dy = tap / 3, dx = tap % 3;
    int cin = hf * 32 + (lane >> 4) * 8 + j;
    float v = (n < creal) ? w[((n * 64 + cin) * 3 + dy) * 3 + dx] : 0.f;
    bp[idx] = f2bf(v);
}

// ---- conv3x3 1->64 + bias + relu, fp32 in, bf16 NHWC out --------------------
__global__ __launch_bounds__(256) void conv_1to64(
    const float* __restrict__ x, const float* __restrict__ w,
    const float* __restrict__ b, unsigned short* __restrict__ out) {
    __shared__ float wt[9 * 64];
    __shared__ float bt[64];
    int tid = threadIdx.x;
    for (int i = tid; i < 576; i += 256) {
        int c = i & 63, tap = i >> 6;
        wt[tap * 64 + c] = w[c * 9 + tap];
    }
    if (tid < 64) bt[tid] = b[tid];
    __syncthreads();
    int wi = tid >> 6, c = tid & 63;
    int pix0 = blockIdx.x * 64 + wi * 16;          // first pixel of this wave
    int wcol0 = pix0 & 255, hrow = (pix0 >> 8) & 255, n = pix0 >> 16;
    const float* xb = x + ((size_t)n << 16);
    float acc[16];
    float bb = bt[c];
    #pragma unroll
    for (int p = 0; p < 16; p++) acc[p] = bb;
    #pragma unroll
    for (int dy = 0; dy < 3; dy++) {
        int hy = hrow + dy - 1;
        if (hy < 0 || hy > 255) continue;          // wave-uniform
        const float* rp = xb + (hy << 8) + wcol0;
        float row[18];
        #pragma unroll
        for (int j = 0; j < 18; j++) {
            int gw = wcol0 - 1 + j;
            row[j] = (gw >= 0 && gw < 256) ? rp[j - 1] : 0.f;
        }
        #pragma unroll
        for (int dx = 0; dx < 3; dx++) {
            float wv = wt[(dy * 3 + dx) * 64 + c];
            #pragma unroll
            for (int p = 0; p < 16; p++) acc[p] += row[p + dx] * wv;
        }
    }
    size_t ob = ((size_t)pix0 << 6) + c;
    #pragma unroll
    for (int p = 0; p < 16; p++)
        out[ob + ((size_t)p << 6)] = f2bf(fmaxf(acc[p], 0.f));
}

// ---- conv3x3 2->64 + bias + relu, fp32 [pix][2] in, bf16 NHWC out -----------
__global__ __launch_bounds__(256) void conv_2to64(
    const float* __restrict__ hin, const float* __restrict__ w,
    const float* __restrict__ b, unsigned short* __restrict__ out) {
    __shared__ float wt[18 * 64];
    __shared__ float bt[64];
    int tid = threadIdx.x;
    for (int i = tid; i < 1152; i += 256) {
        int c = i & 63, tc = i >> 6;     // tc = tap*2 + ci
        int tap = tc >> 1, ci = tc & 1;
        wt[tc * 64 + c] = w[(c * 2 + ci) * 9 + tap];
    }
    if (tid < 64) bt[tid] = b[tid];
    __syncthreads();
    int wi = tid >> 6, c = tid & 63;
    int pix0 = blockIdx.x * 64 + wi * 16;
    int wcol0 = pix0 & 255, hrow = (pix0 >> 8) & 255, n = pix0 >> 16;
    const float* hb = hin + ((size_t)n << 17);
    float acc[16];
    float bb = bt[c];
    #pragma unroll
    for (int p = 0; p < 16; p++) acc[p] = bb;
    #pragma unroll
    for (int dy = 0; dy < 3; dy++) {
        int hy = hrow + dy - 1;
        if (hy < 0 || hy > 255) continue;          // wave-uniform
        const float* rp = hb + (((hy << 8) + wcol0) << 1);
        float rx[18], ry[18];
        #pragma unroll
        for (int j = 0; j < 18; j++) {
            int gw = wcol0 - 1 + j;
            bool ok = (gw >= 0 && gw < 256);
            float2 vv = ok ? *(const float2*)(rp + ((j - 1) << 1)) : float2{0.f, 0.f};
            rx[j] = vv.x; ry[j] = vv.y;
        }
        #pragma unroll
        for (int dx = 0; dx < 3; dx++) {
            int tap = dy * 3 + dx;
            float w0 = wt[(tap * 2 + 0) * 64 + c];
            float w1 = wt[(tap * 2 + 1) * 64 + c];
            #pragma unroll
            for (int p = 0; p < 16; p++)
                acc[p] += rx[p + dx] * w0 + ry[p + dx] * w1;
        }
    }
    size_t ob = ((size_t)pix0 << 6) + c;
    #pragma unroll
    for (int p = 0; p < 16; p++)
        out[ob + ((size_t)p << 6)] = f2bf(fmaxf(acc[p], 0.f));
}

// ---- conv3x3 64->NG*16 + bias + relu via MFMA (implicit GEMM) ---------------
// 512 threads = 8 waves; wave w handles row (w>>1), col-half (w&1)*32: 2 m-tiles.
template <int NG>
__global__ __launch_bounds__(512, 4) void conv_mfma(
    const unsigned short* __restrict__ hin, const unsigned short* __restrict__ bp,
    const float* __restrict__ bias, unsigned short* __restrict__ hout) {
    __shared__ __align__(16) unsigned short tile[6 * 66 * 72];
    int blk = blockIdx.x;
    int n = blk >> 8;
    int rem = blk & 255;
    int h0 = (rem >> 2) * 4;
    int w0 = (rem & 3) * 64;
    int tid = threadIdx.x;
    const unsigned short* hb = hin + ((size_t)n << 22);
    for (int c = tid; c < 6 * 66 * 8; c += 512) {
        int ch8 = c & 7;
        int cc = (c >> 3) % 66;
        int rr = (c >> 3) / 66;
        int gh = h0 - 1 + rr, gw = w0 - 1 + cc;
        uint4 v = {0u, 0u, 0u, 0u};
        if (gh >= 0 && gh < 256 && gw >= 0 && gw < 256)
            v = *(const uint4*)(hb + (((gh << 8) + gw) << 6) + ch8 * 8);
        *(uint4*)(tile + (rr * 66 + cc) * 72 + ch8 * 8) = v;
    }
    __syncthreads();
    int lane = tid & 63, w = tid >> 6;
    int row = w >> 1, cb = (w & 1) * 32;          // col base of this wave
    int nl = lane & 15, quad = lane >> 4;
    floatx4 acc[2][NG];
    floatx4 zero = {0.f, 0.f, 0.f, 0.f};
    #pragma unroll
    for (int mi = 0; mi < 2; mi++)
        #pragma unroll
        for (int g = 0; g < NG; g++) acc[mi][g] = zero;
    #pragma unroll
    for (int t = 0; t < 18; t++) {
        const int tap = t >> 1, hf = t & 1;
        const int dy = tap / 3, dx = tap % 3;
        short8 A[2];
        #pragma unroll
        for (int mi = 0; mi < 2; mi++)
            A[mi] = *(const short8*)(tile + ((row + dy) * 66 + cb + mi * 16 + nl + dx) * 72 + hf * 32 + quad * 8);
        #pragma unroll
        for (int g = 0; g < NG; g++) {
            short8 B = *(const short8*)(bp + (((g * 18 + t) << 6) + lane) * 8);
            #pragma unroll
            for (int mi = 0; mi < 2; mi++)
                acc[mi][g] = __builtin_amdgcn_mfma_f32_16x16x32_bf16(A[mi], B, acc[mi][g], 0, 0, 0);
        }
    }
    size_t obase = ((size_t)((n * 256 + h0 + row)) << 8) + w0 + cb;
    #pragma unroll
    for (int g = 0; g < NG; g++) {
        float bb = bias[g * 16 + nl];
        #pragma unroll
        for (int mi = 0; mi < 2; mi++) {
            #pragma unroll
            for (int r = 0; r < 4; r++) {
                int pc = mi * 16 + quad * 4 + r;
                float v = fmaxf(acc[mi][g][r] + bb, 0.f);
                hout[(obase + pc) * (NG * 16) + g * 16 + nl] = f2bf(v);
            }
        }
    }
}

// ---- conv3x3 64->81 (pad 96) + bias + softmax(81) + 9x9 adaptive filter -----
// 512 threads. MFMA phase like conv_mfma<6>; then logits -> LDS (bf16, stride
// 104), and 256 threads do per-pixel softmax+apply (no shuffles, no gathers).
__global__ __launch_bounds__(512, 4) void conv_softmax_apply(
    const unsigned short* __restrict__ h2b, const unsigned short* __restrict__ bp,
    const float* __restrict__ bias, const float* __restrict__ x,
    float* __restrict__ hout, int head) {
    __shared__ __align__(16) unsigned short tile[6 * 66 * 72];  // also reused for logits (256*104)
    __shared__ __align__(16) float xt[12 * 72];
    int blk = blockIdx.x;
    int n = blk >> 8;
    int rem = blk & 255;
    int h0 = (rem >> 2) * 4;
    int w0 = (rem & 3) * 64;
    int tid = threadIdx.x;
    const unsigned short* hb = h2b + ((size_t)n << 22);
    for (int c = tid; c < 6 * 66 * 8; c += 512) {
        int ch8 = c & 7;
        int cc = (c >> 3) % 66;
        int rr = (c >> 3) / 66;
        int gh = h0 - 1 + rr, gw = w0 - 1 + cc;
        uint4 v = {0u, 0u, 0u, 0u};
        if (gh >= 0 && gh < 256 && gw >= 0 && gw < 256)
            v = *(const uint4*)(hb + (((gh << 8) + gw) << 6) + ch8 * 8);
        *(uint4*)(tile + (rr * 66 + cc) * 72 + ch8 * 8) = v;
    }
    const float* xb = x + ((size_t)n << 16);
    for (int c = tid; c < 12 * 72; c += 512) {
        int cc = c % 72, rr = c / 72;
        int gh = h0 - 4 + rr, gw = w0 - 4 + cc;
        xt[c] = (gh >= 0 && gh < 256 && gw >= 0 && gw < 256) ? xb[(gh << 8) + gw] : 0.f;
    }
    __syncthreads();
    int lane = tid & 63, w = tid >> 6;
    int row = w >> 1, cb = (w & 1) * 32;
    int nl = lane & 15, quad = lane >> 4;
    floatx4 acc[2][6];
    floatx4 zero = {0.f, 0.f, 0.f, 0.f};
    #pragma unroll
    for (int mi = 0; mi < 2; mi++)
        #pragma unroll
        for (int g = 0; g < 6; g++) acc[mi][g] = zero;
    #pragma unroll
    for (int t = 0; t < 18; t++) {
        const int tap = t >> 1, hf = t & 1;
        const int dy = tap / 3, dx = tap % 3;
        short8 A[2];
        #pragma unroll
        for (int mi = 0; mi < 2; mi++)
            A[mi] = *(const short8*)(tile + ((row + dy) * 66 + cb + mi * 16 + nl + dx) * 72 + hf * 32 + quad * 8);
        #pragma unroll
        for (int g = 0; g < 6; g++) {
            short8 B = *(const short8*)(bp + (((g * 18 + t) << 6) + lane) * 8);
            #pragma unroll
            for (int mi = 0; mi < 2; mi++)
                acc[mi][g] = __builtin_amdgcn_mfma_f32_16x16x32_bf16(A[mi], B, acc[mi][g], 0, 0, 0);
        }
    }
    __syncthreads();   // MFMA loop done everywhere; safe to overwrite tile
    // write logits (bias added) to LDS in [pixel][channel] layout, bf16, stride 104
    #pragma unroll
    for (int g = 0; g < 6; g++) {
        int ch = g * 16 + nl;
        float bb = (ch < 81) ? bias[ch] : 0.f;
        #pragma unroll
        for (int mi = 0; mi < 2; mi++) {
            #pragma unroll
            for (int r = 0; r < 4; r++) {
                int pl = row * 64 + cb + mi * 16 + quad * 4 + r;   // pixel-local 0..255
                tile[pl * 104 + ch] = f2bf(acc[mi][g][r] + bb);
            }
        }
    }
    __syncthreads();
    if (tid >= 256) return;
    // per-pixel softmax over 81 + 9x9 apply
    int pl = tid;
    int r0 = pl >> 6, c0 = pl & 63;
    const unsigned short* lgp = tile + pl * 104;
    short8 lg8[12];
    #pragma unroll
    for (int jj = 0; jj < 12; jj++) lg8[jj] = *(const short8*)(lgp + jj * 8);
    float m = -1e30f;
    #pragma unroll
    for (int ch = 0; ch < 81; ch++) {
        float v = bf2f((unsigned short)lg8[ch >> 3][ch & 7]);
        m = fmaxf(m, v);
    }
    float sum = 0.f, dot = 0.f;
    #pragma unroll
    for (int ch = 0; ch < 81; ch++) {
        float v = bf2f((unsigned short)lg8[ch >> 3][ch & 7]);
        float e = __expf(v - m);
        sum += e;
        dot += e * xt[(r0 + ch / 9) * 72 + c0 + (ch % 9)];
    }
    size_t gp = ((size_t)((n * 256 + h0 + r0)) << 8) + w0 + c0;
    hout[gp * 2 + head] = dot / sum;
}

// ---- conv3x3 64->1 + bias, bf16 NHWC in, fp32 out ---------------------------
__global__ void conv_64to1(const unsigned short* __restrict__ h2,
                           const float* __restrict__ w, const float* __restrict__ b,
                           float* __restrict__ out) {
    __shared__ __align__(16) float wt[9 * 64];
    int tid = threadIdx.x;
    for (int i = tid; i < 576; i += 256) {
        int c = i & 63, tap = i >> 6;
        wt[tap * 64 + c] = w[c * 9 + tap];
    }
    __syncthreads();
    int pix = blockIdx.x * 256 + tid;
    int wcol = pix & 255, hrow = (pix >> 8) & 255, n = pix >> 16;
    float acc = b[0];
    #pragma unroll
    for (int dy = 0; dy < 3; dy++) {
        int hy = hrow + dy - 1;
        if (hy < 0 || hy > 255) continue;
        #pragma unroll
        for (int dx = 0; dx < 3; dx++) {
            int wx = wcol + dx - 1;
            if (wx < 0 || wx > 255) continue;
            const uint4* p4 = (const uint4*)(h2 + ((size_t)((n * 256 + hy) * 256 + wx) << 6));
            const float* wp = wt + (dy * 3 + dx) * 64;
            #pragma unroll
            for (int c8 = 0; c8 < 8; c8++) {
                uint4 vv = p4[c8];
                unsigned int vs[4] = {vv.x, vv.y, vv.z, vv.w};
                #pragma unroll
                for (int k = 0; k < 4; k++) {
                    acc += __uint_as_float(vs[k] << 16) * wp[c8 * 8 + 2 * k];
                    acc += __uint_as_float(vs[k] & 0xffff0000u) * wp[c8 * 8 + 2 * k + 1];
                }
            }
        }
    }
    out[pix] = acc;
}

extern "C" void kernel_launch(void* const* d_in, const int* in_sizes, int n_in,
                              void* d_out, int out_size, void* d_ws, size_t ws_size,
                              hipStream_t stream) {
    const float* x     = (const float*)d_in[0];
    const float* g     = (const float*)d_in[1];
    const float* fx_w1 = (const float*)d_in[2];
    const float* fx_b1 = (const float*)d_in[3];
    const float* fx_w2 = (const float*)d_in[4];
    const float* fx_b2 = (const float*)d_in[5];
    const float* fx_w3 = (const float*)d_in[6];
    const float* fx_b3 = (const float*)d_in[7];
    const float* fg_w1 = (const float*)d_in[8];
    const float* fg_b1 = (const float*)d_in[9];
    const float* fg_w2 = (const float*)d_in[10];
    const float* fg_b2 = (const float*)d_in[11];
    const float* fg_w3 = (const float*)d_in[12];
    const float* fg_b3 = (const float*)d_in[13];
    const float* c1_w  = (const float*)d_in[14];
    const float* c1_b  = (const float*)d_in[15];
    const float* c2_w  = (const float*)d_in[16];
    const float* c2_b  = (const float*)d_in[17];
    const float* c3_w  = (const float*)d_in[18];
    const float* c3_b  = (const float*)d_in[19];
    float* out = (float*)d_out;

    // ---- adaptive workspace layout ------------------------------------------
    const size_t packElems = 221184;   // 5 packs, bf16 elements
    const size_t fixedB = (size_t)P_TOT * 2 * sizeof(float) + packElems * 2 + 256;
    int c = 16;
    while (c > 1 && fixedB + (size_t)c * P_IMG * 256 > ws_size) c >>= 1;
    size_t pcElems = (size_t)c * P_IMG * 64;   // bf16 elements per chunk buffer

    unsigned short* h1 = (unsigned short*)d_ws;
    unsigned short* h2 = h1 + pcElems;
    float* hin = (float*)(h2 + pcElems);
    unsigned short* bp0 = (unsigned short*)(hin + (size_t)P_TOT * 2);
    unsigned short* bp_w2x = bp0;
    unsigned short* bp_w3x = bp0 + 36864;
    unsigned short* bp_w2g = bp0 + 92160;
    unsigned short* bp_w3g = bp0 + 129024;
    unsigned short* bp_c2  = bp0 + 184320;

    dim3 blk(256);
    dim3 blk512(512);
    repack_w<<<144, blk, 0, stream>>>(fx_w2, bp_w2x, 4, 64);
    repack_w<<<216, blk, 0, stream>>>(fx_w3, bp_w3x, 6, 81);
    repack_w<<<144, blk, 0, stream>>>(fg_w2, bp_w2g, 4, 64);
    repack_w<<<216, blk, 0, stream>>>(fg_w3, bp_w3g, 6, 81);
    repack_w<<<144, blk, 0, stream>>>(c2_w,  bp_c2,  4, 64);

    const int nchunk = 16 / c;
    // heads x and g -> hin
    for (int ck = 0; ck < nchunk; ck++) {
        size_t po = (size_t)ck * c * P_IMG;       // pixel offset of chunk
        conv_1to64<<<c * P_IMG / 64, blk, 0, stream>>>(x + po, fx_w1, fx_b1, h1);
        conv_mfma<4><<<c * 256, blk512, 0, stream>>>(h1, bp_w2x, fx_b2, h2);
        conv_softmax_apply<<<c * 256, blk512, 0, stream>>>(h2, bp_w3x, fx_b3, x + po, hin + po * 2, 0);
    }
    for (int ck = 0; ck < nchunk; ck++) {
        size_t po = (size_t)ck * c * P_IMG;
        conv_1to64<<<c * P_IMG / 64, blk, 0, stream>>>(g + po, fg_w1, fg_b1, h1);
        conv_mfma<4><<<c * 256, blk512, 0, stream>>>(h1, bp_w2g, fg_b2, h2);
        conv_softmax_apply<<<c * 256, blk512, 0, stream>>>(h2, bp_w3g, fg_b3, g + po, hin + po * 2, 1);
    }
    // fusion head
    for (int ck = 0; ck < nchunk; ck++) {
        size_t po = (size_t)ck * c * P_IMG;
        conv_2to64<<<c * P_IMG / 64, blk, 0, stream>>>(hin + po * 2, c1_w, c1_b, h1);
        conv_mfma<4><<<c * 256, blk512, 0, stream>>>(h1, bp_c2, c2_b, h2);
        conv_64to1<<<c * P_IMG / 256, blk, 0, stream>>>(h2, c3_w, c3_b, out + po);
    }
}

// Round 6
// 1112.232 us; speedup vs baseline: 1.1525x; 1.1525x over previous
//
#include <hip/hip_runtime.h>
#include <stdint.h>

typedef __attribute__((ext_vector_type(8))) short short8;
typedef __attribute__((ext_vector_type(4))) float floatx4;

#define P_TOT (16 * 256 * 256)
#define P_IMG 65536

__device__ __forceinline__ unsigned short f2bf(float f) {
    unsigned int u = __float_as_uint(f);
    return (unsigned short)((u + 0x7FFFu + ((u >> 16) & 1u)) >> 16);
}
__device__ __forceinline__ float bf2f(unsigned short h) {
    return __uint_as_float(((unsigned int)h) << 16);
}

// ---- repack OIHW fp32 weights -> bf16 MFMA B-fragment order -----------------
__global__ void repack_w(const float* __restrict__ w, unsigned short* __restrict__ bp,
                         int ngroups, int creal) {
    int idx = blockIdx.x * 256 + threadIdx.x;
    if (idx >= ngroups * 9216) return;
    int j = idx & 7;
    int lane = (idx >> 3) & 63;
    int gt = idx >> 9;            // g*18 + t
    int t = gt % 18;
    int n = (gt / 18) * 16 + (lane & 15);
    int tap = t >> 1, hf = t & 1;
    int dy = tap / 3, dx = tap % 3;
    int cin = hf * 32 + (lane >> 4) * 8 + j;
    float v = (n < creal) ? w[((n * 64 + cin) * 3 + dy) * 3 + dx] : 0.f;
    bp[idx] = f2bf(v);
}

// ---- conv3x3 1->64 + bias + relu, fp32 in, bf16 NHWC out --------------------
__global__ __launch_bounds__(256) void conv_1to64(
    const float* __restrict__ x, const float* __restrict__ w,
    const float* __restrict__ b, unsigned short* __restrict__ out) {
    __shared__ float wt[9 * 64];
    __shared__ float bt[64];
    int tid = threadIdx.x;
    for (int i = tid; i < 576; i += 256) {
        int c = i & 63, tap = i >> 6;
        wt[tap * 64 + c] = w[c * 9 + tap];
    }
    if (tid < 64) bt[tid] = b[tid];
    __syncthreads();
    int wi = tid >> 6, c = tid & 63;
    int pix0 = blockIdx.x * 64 + wi * 16;          // first pixel of this wave
    int wcol0 = pix0 & 255, hrow = (pix0 >> 8) & 255, n = pix0 >> 16;
    const float* xb = x + ((size_t)n << 16);
    float acc[16];
    float bb = bt[c];
    #pragma unroll
    for (int p = 0; p < 16; p++) acc[p] = bb;
    #pragma unroll
    for (int dy = 0; dy < 3; dy++) {
        int hy = hrow + dy - 1;
        if (hy < 0 || hy > 255) continue;          // wave-uniform
        const float* rp = xb + (hy << 8) + wcol0;
        float row[18];
        #pragma unroll
        for (int j = 0; j < 18; j++) {
            int gw = wcol0 - 1 + j;
            row[j] = (gw >= 0 && gw < 256) ? rp[j - 1] : 0.f;
        }
        #pragma unroll
        for (int dx = 0; dx < 3; dx++) {
            float wv = wt[(dy * 3 + dx) * 64 + c];
            #pragma unroll
            for (int p = 0; p < 16; p++) acc[p] += row[p + dx] * wv;
        }
    }
    size_t ob = ((size_t)pix0 << 6) + c;
    #pragma unroll
    for (int p = 0; p < 16; p++)
        out[ob + ((size_t)p << 6)] = f2bf(fmaxf(acc[p], 0.f));
}

// ---- conv3x3 2->64 + bias + relu, fp32 [pix][2] in, bf16 NHWC out -----------
__global__ __launch_bounds__(256) void conv_2to64(
    const float* __restrict__ hin, const float* __restrict__ w,
    const float* __restrict__ b, unsigned short* __restrict__ out) {
    __shared__ float wt[18 * 64];
    __shared__ float bt[64];
    int tid = threadIdx.x;
    for (int i = tid; i < 1152; i += 256) {
        int c = i & 63, tc = i >> 6;     // tc = tap*2 + ci
        int tap = tc >> 1, ci = tc & 1;
        wt[tc * 64 + c] = w[(c * 2 + ci) * 9 + tap];
    }
    if (tid < 64) bt[tid] = b[tid];
    __syncthreads();
    int wi = tid >> 6, c = tid & 63;
    int pix0 = blockIdx.x * 64 + wi * 16;
    int wcol0 = pix0 & 255, hrow = (pix0 >> 8) & 255, n = pix0 >> 16;
    const float* hb = hin + ((size_t)n << 17);
    float acc[16];
    float bb = bt[c];
    #pragma unroll
    for (int p = 0; p < 16; p++) acc[p] = bb;
    #pragma unroll
    for (int dy = 0; dy < 3; dy++) {
        int hy = hrow + dy - 1;
        if (hy < 0 || hy > 255) continue;          // wave-uniform
        const float* rp = hb + (((hy << 8) + wcol0) << 1);
        float rx[18], ry[18];
        #pragma unroll
        for (int j = 0; j < 18; j++) {
            int gw = wcol0 - 1 + j;
            bool ok = (gw >= 0 && gw < 256);
            float2 vv = ok ? *(const float2*)(rp + ((j - 1) << 1)) : float2{0.f, 0.f};
            rx[j] = vv.x; ry[j] = vv.y;
        }
        #pragma unroll
        for (int dx = 0; dx < 3; dx++) {
            int tap = dy * 3 + dx;
            float w0 = wt[(tap * 2 + 0) * 64 + c];
            float w1 = wt[(tap * 2 + 1) * 64 + c];
            #pragma unroll
            for (int p = 0; p < 16; p++)
                acc[p] += rx[p + dx] * w0 + ry[p + dx] * w1;
        }
    }
    size_t ob = ((size_t)pix0 << 6) + c;
    #pragma unroll
    for (int p = 0; p < 16; p++)
        out[ob + ((size_t)p << 6)] = f2bf(fmaxf(acc[p], 0.f));
}

// ---- conv3x3 64->NG*16 + bias + relu via MFMA (implicit GEMM) ---------------
// 512 threads = 8 waves; wave w: row = w&3 (full 64-px row, 4 m-tiles),
// g-half = w>>2 (NG/2 output groups). Halves per-block B traffic vs all-g waves.
template <int NG>
__global__ __launch_bounds__(512, 4) void conv_mfma(
    const unsigned short* __restrict__ hin, const unsigned short* __restrict__ bp,
    const float* __restrict__ bias, unsigned short* __restrict__ hout) {
    constexpr int GH = NG / 2;
    __shared__ __align__(16) unsigned short tile[6 * 66 * 72];
    int blk = blockIdx.x;
    int n = blk >> 8;
    int rem = blk & 255;
    int h0 = (rem >> 2) * 4;
    int w0 = (rem & 3) * 64;
    int tid = threadIdx.x;
    const unsigned short* hb = hin + ((size_t)n << 22);
    for (int c = tid; c < 6 * 66 * 8; c += 512) {
        int ch8 = c & 7;
        int cc = (c >> 3) % 66;
        int rr = (c >> 3) / 66;
        int gh = h0 - 1 + rr, gw = w0 - 1 + cc;
        uint4 v = {0u, 0u, 0u, 0u};
        if (gh >= 0 && gh < 256 && gw >= 0 && gw < 256)
            v = *(const uint4*)(hb + (((gh << 8) + gw) << 6) + ch8 * 8);
        *(uint4*)(tile + (rr * 66 + cc) * 72 + ch8 * 8) = v;
    }
    __syncthreads();
    int lane = tid & 63, w = tid >> 6;
    int row = w & 3, ghalf = w >> 2;
    int nl = lane & 15, quad = lane >> 4;
    floatx4 acc[4][GH];
    floatx4 zero = {0.f, 0.f, 0.f, 0.f};
    #pragma unroll
    for (int mi = 0; mi < 4; mi++)
        #pragma unroll
        for (int g = 0; g < GH; g++) acc[mi][g] = zero;
    #pragma unroll
    for (int t = 0; t < 18; t++) {
        const int tap = t >> 1, hf = t & 1;
        const int dy = tap / 3, dx = tap % 3;
        short8 A[4];
        #pragma unroll
        for (int mi = 0; mi < 4; mi++)
            A[mi] = *(const short8*)(tile + ((row + dy) * 66 + mi * 16 + nl + dx) * 72 + hf * 32 + quad * 8);
        #pragma unroll
        for (int g = 0; g < GH; g++) {
            short8 B = *(const short8*)(bp + ((((ghalf * GH + g) * 18 + t) << 6) + lane) * 8);
            #pragma unroll
            for (int mi = 0; mi < 4; mi++)
                acc[mi][g] = __builtin_amdgcn_mfma_f32_16x16x32_bf16(A[mi], B, acc[mi][g], 0, 0, 0);
        }
    }
    size_t obase = ((size_t)((n * 256 + h0 + row)) << 8) + w0;
    #pragma unroll
    for (int g = 0; g < GH; g++) {
        int gg = ghalf * GH + g;
        float bb = bias[gg * 16 + nl];
        #pragma unroll
        for (int mi = 0; mi < 4; mi++) {
            #pragma unroll
            for (int r = 0; r < 4; r++) {
                int pc = mi * 16 + quad * 4 + r;
                float v = fmaxf(acc[mi][g][r] + bb, 0.f);
                hout[(obase + pc) * (NG * 16) + gg * 16 + nl] = f2bf(v);
            }
        }
    }
}

// ---- conv3x3 64->81 (pad 96) + bias + softmax(81) + 9x9 adaptive filter -----
// 512 threads; wave w: row = w&3, g-half = w>>2 (3 of 6 groups). Then logits ->
// LDS (bf16, stride 104) and 256 threads do per-pixel softmax+apply.
__global__ __launch_bounds__(512, 4) void conv_softmax_apply(
    const unsigned short* __restrict__ h2b, const unsigned short* __restrict__ bp,
    const float* __restrict__ bias, const float* __restrict__ x,
    float* __restrict__ hout, int head) {
    __shared__ __align__(16) unsigned short tile[6 * 66 * 72];  // reused for logits (256*104)
    __shared__ __align__(16) float xt[12 * 72];
    int blk = blockIdx.x;
    int n = blk >> 8;
    int rem = blk & 255;
    int h0 = (rem >> 2) * 4;
    int w0 = (rem & 3) * 64;
    int tid = threadIdx.x;
    const unsigned short* hb = h2b + ((size_t)n << 22);
    for (int c = tid; c < 6 * 66 * 8; c += 512) {
        int ch8 = c & 7;
        int cc = (c >> 3) % 66;
        int rr = (c >> 3) / 66;
        int gh = h0 - 1 + rr, gw = w0 - 1 + cc;
        uint4 v = {0u, 0u, 0u, 0u};
        if (gh >= 0 && gh < 256 && gw >= 0 && gw < 256)
            v = *(const uint4*)(hb + (((gh << 8) + gw) << 6) + ch8 * 8);
        *(uint4*)(tile + (rr * 66 + cc) * 72 + ch8 * 8) = v;
    }
    const float* xb = x + ((size_t)n << 16);
    for (int c = tid; c < 12 * 72; c += 512) {
        int cc = c % 72, rr = c / 72;
        int gh = h0 - 4 + rr, gw = w0 - 4 + cc;
        xt[c] = (gh >= 0 && gh < 256 && gw >= 0 && gw < 256) ? xb[(gh << 8) + gw] : 0.f;
    }
    __syncthreads();
    int lane = tid & 63, w = tid >> 6;
    int row = w & 3, ghalf = w >> 2;
    int nl = lane & 15, quad = lane >> 4;
    floatx4 acc[4][3];
    floatx4 zero = {0.f, 0.f, 0.f, 0.f};
    #pragma unroll
    for (int mi = 0; mi < 4; mi++)
        #pragma unroll
        for (int g = 0; g < 3; g++) acc[mi][g] = zero;
    #pragma unroll
    for (int t = 0; t < 18; t++) {
        const int tap = t >> 1, hf = t & 1;
        const int dy = tap / 3, dx = tap % 3;
        short8 A[4];
        #pragma unroll
        for (int mi = 0; mi < 4; mi++)
            A[mi] = *(const short8*)(tile + ((row + dy) * 66 + mi * 16 + nl + dx) * 72 + hf * 32 + quad * 8);
        #pragma unroll
        for (int g = 0; g < 3; g++) {
            short8 B = *(const short8*)(bp + ((((ghalf * 3 + g) * 18 + t) << 6) + lane) * 8);
            #pragma unroll
            for (int mi = 0; mi < 4; mi++)
                acc[mi][g] = __builtin_amdgcn_mfma_f32_16x16x32_bf16(A[mi], B, acc[mi][g], 0, 0, 0);
        }
    }
    __syncthreads();   // all waves done reading tile
    // logits (bias added) -> LDS [pixel][channel], bf16, stride 104
    #pragma unroll
    for (int g = 0; g < 3; g++) {
        int ch = (ghalf * 3 + g) * 16 + nl;
        float bb = (ch < 81) ? bias[ch] : 0.f;
        #pragma unroll
        for (int mi = 0; mi < 4; mi++) {
            #pragma unroll
            for (int r = 0; r < 4; r++) {
                int pl = row * 64 + mi * 16 + quad * 4 + r;   // pixel-local 0..255
                tile[pl * 104 + ch] = f2bf(acc[mi][g][r] + bb);
            }
        }
    }
    __syncthreads();
    if (tid >= 256) return;
    // per-pixel softmax over 81 + 9x9 apply
    int pl = tid;
    int r0 = pl >> 6, c0 = pl & 63;
    const unsigned short* lgp = tile + pl * 104;
    short8 lg8[12];
    #pragma unroll
    for (int jj = 0; jj < 12; jj++) lg8[jj] = *(const short8*)(lgp + jj * 8);
    float m = -1e30f;
    #pragma unroll
    for (int ch = 0; ch < 81; ch++) {
        float v = bf2f((unsigned short)lg8[ch >> 3][ch & 7]);
        m = fmaxf(m, v);
    }
    float sum = 0.f, dot = 0.f;
    #pragma unroll
    for (int ch = 0; ch < 81; ch++) {
        float v = bf2f((unsigned short)lg8[ch >> 3][ch & 7]);
        float e = __expf(v - m);
        sum += e;
        dot += e * xt[(r0 + ch / 9) * 72 + c0 + (ch % 9)];
    }
    size_t gp = ((size_t)((n * 256 + h0 + r0)) << 8) + w0 + c0;
    hout[gp * 2 + head] = dot / sum;
}

// ---- conv3x3 64->1 + bias, bf16 NHWC in, fp32 out ---------------------------
__global__ void conv_64to1(const unsigned short* __restrict__ h2,
                           const float* __restrict__ w, const float* __restrict__ b,
                           float* __restrict__ out) {
    __shared__ __align__(16) float wt[9 * 64];
    int tid = threadIdx.x;
    for (int i = tid; i < 576; i += 256) {
        int c = i & 63, tap = i >> 6;
        wt[tap * 64 + c] = w[c * 9 + tap];
    }
    __syncthreads();
    int pix = blockIdx.x * 256 + tid;
    int wcol = pix & 255, hrow = (pix >> 8) & 255, n = pix >> 16;
    float acc = b[0];
    #pragma unroll
    for (int dy = 0; dy < 3; dy++) {
        int hy = hrow + dy - 1;
        if (hy < 0 || hy > 255) continue;
        #pragma unroll
        for (int dx = 0; dx < 3; dx++) {
            int wx = wcol + dx - 1;
            if (wx < 0 || wx > 255) continue;
            const uint4* p4 = (const uint4*)(h2 + ((size_t)((n * 256 + hy) * 256 + wx) << 6));
            const float* wp = wt + (dy * 3 + dx) * 64;
            #pragma unroll
            for (int c8 = 0; c8 < 8; c8++) {
                uint4 vv = p4[c8];
                unsigned int vs[4] = {vv.x, vv.y, vv.z, vv.w};
                #pragma unroll
                for (int k = 0; k < 4; k++) {
                    acc += __uint_as_float(vs[k] << 16) * wp[c8 * 8 + 2 * k];
                    acc += __uint_as_float(vs[k] & 0xffff0000u) * wp[c8 * 8 + 2 * k + 1];
                }
            }
        }
    }
    out[pix] = acc;
}

extern "C" void kernel_launch(void* const* d_in, const int* in_sizes, int n_in,
                              void* d_out, int out_size, void* d_ws, size_t ws_size,
                              hipStream_t stream) {
    const float* x     = (const float*)d_in[0];
    const float* g     = (const float*)d_in[1];
    const float* fx_w1 = (const float*)d_in[2];
    const float* fx_b1 = (const float*)d_in[3];
    const float* fx_w2 = (const float*)d_in[4];
    const float* fx_b2 = (const float*)d_in[5];
    const float* fx_w3 = (const float*)d_in[6];
    const float* fx_b3 = (const float*)d_in[7];
    const float* fg_w1 = (const float*)d_in[8];
    const float* fg_b1 = (const float*)d_in[9];
    const float* fg_w2 = (const float*)d_in[10];
    const float* fg_b2 = (const float*)d_in[11];
    const float* fg_w3 = (const float*)d_in[12];
    const float* fg_b3 = (const float*)d_in[13];
    const float* c1_w  = (const float*)d_in[14];
    const float* c1_b  = (const float*)d_in[15];
    const float* c2_w  = (const float*)d_in[16];
    const float* c2_b  = (const float*)d_in[17];
    const float* c3_w  = (const float*)d_in[18];
    const float* c3_b  = (const float*)d_in[19];
    float* out = (float*)d_out;

    // ---- adaptive workspace layout ------------------------------------------
    const size_t packElems = 221184;   // 5 packs, bf16 elements
    const size_t fixedB = (size_t)P_TOT * 2 * sizeof(float) + packElems * 2 + 256;
    int c = 16;
    while (c > 1 && fixedB + (size_t)c * P_IMG * 256 > ws_size) c >>= 1;
    size_t pcElems = (size_t)c * P_IMG * 64;   // bf16 elements per chunk buffer

    unsigned short* h1 = (unsigned short*)d_ws;
    unsigned short* h2 = h1 + pcElems;
    float* hin = (float*)(h2 + pcElems);
    unsigned short* bp0 = (unsigned short*)(hin + (size_t)P_TOT * 2);
    unsigned short* bp_w2x = bp0;
    unsigned short* bp_w3x = bp0 + 36864;
    unsigned short* bp_w2g = bp0 + 92160;
    unsigned short* bp_w3g = bp0 + 129024;
    unsigned short* bp_c2  = bp0 + 184320;

    dim3 blk(256);
    dim3 blk512(512);
    repack_w<<<144, blk, 0, stream>>>(fx_w2, bp_w2x, 4, 64);
    repack_w<<<216, blk, 0, stream>>>(fx_w3, bp_w3x, 6, 81);
    repack_w<<<144, blk, 0, stream>>>(fg_w2, bp_w2g, 4, 64);
    repack_w<<<216, blk, 0, stream>>>(fg_w3, bp_w3g, 6, 81);
    repack_w<<<144, blk, 0, stream>>>(c2_w,  bp_c2,  4, 64);

    const int nchunk = 16 / c;
    // heads x and g -> hin
    for (int ck = 0; ck < nchunk; ck++) {
        size_t po = (size_t)ck * c * P_IMG;       // pixel offset of chunk
        conv_1to64<<<c * P_IMG / 64, blk, 0, stream>>>(x + po, fx_w1, fx_b1, h1);
        conv_mfma<4><<<c * 256, blk512, 0, stream>>>(h1, bp_w2x, fx_b2, h2);
        conv_softmax_apply<<<c * 256, blk512, 0, stream>>>(h2, bp_w3x, fx_b3, x + po, hin + po * 2, 0);
    }
    for (int ck = 0; ck < nchunk; ck++) {
        size_t po = (size_t)ck * c * P_IMG;
        conv_1to64<<<c * P_IMG / 64, blk, 0, stream>>>(g + po, fg_w1, fg_b1, h1);
        conv_mfma<4><<<c * 256, blk512, 0, stream>>>(h1, bp_w2g, fg_b2, h2);
        conv_softmax_apply<<<c * 256, blk512, 0, stream>>>(h2, bp_w3g, fg_b3, g + po, hin + po * 2, 1);
    }
    // fusion head
    for (int ck = 0; ck < nchunk; ck++) {
        size_t po = (size_t)ck * c * P_IMG;
        conv_2to64<<<c * P_IMG / 64, blk, 0, stream>>>(hin + po * 2, c1_w, c1_b, h1);
        conv_mfma<4><<<c * 256, blk512, 0, stream>>>(h1, bp_c2, c2_b, h2);
        conv_64to1<<<c * P_IMG / 256, blk, 0, stream>>>(h2, c3_w, c3_b, out + po);
    }
}

// Round 7
// 1017.729 us; speedup vs baseline: 1.2595x; 1.0929x over previous
//
#include <hip/hip_runtime.h>
#include <stdint.h>

typedef __attribute__((ext_vector_type(8))) short short8;
typedef __attribute__((ext_vector_type(4))) float floatx4;

#define P_TOT (16 * 256 * 256)
#define P_IMG 65536

__device__ __forceinline__ unsigned short f2bf(float f) {
    unsigned int u = __float_as_uint(f);
    return (unsigned short)((u + 0x7FFFu + ((u >> 16) & 1u)) >> 16);
}
__device__ __forceinline__ float bf2f(unsigned short h) {
    return __uint_as_float(((unsigned int)h) << 16);
}

// ---- repack OIHW fp32 weights -> bf16 MFMA B-fragment order -----------------
__global__ void repack_w(const float* __restrict__ w, unsigned short* __restrict__ bp,
                         int ngroups, int creal) {
    int idx = blockIdx.x * 256 + threadIdx.x;
    if (idx >= ngroups * 9216) return;
    int j = idx & 7;
    int lane = (idx >> 3) & 63;
    int gt = idx >> 9;            // g*18 + t
    int t = gt % 18;
    int n = (gt / 18) * 16 + (lane & 15);
    int tap = t >> 1, hf = t & 1;
    int dy = tap / 3, dx = tap % 3;
    int cin = hf * 32 + (lane >> 4) * 8 + j;
    float v = (n < creal) ? w[((n * 64 + cin) * 3 + dy) * 3 + dx] : 0.f;
    bp[idx] = f2bf(v);
}

// ---- conv3x3 1->64 + bias + relu, fp32 in, bf16 NHWC out --------------------
__global__ __launch_bounds__(256) void conv_1to64(
    const float* __restrict__ x, const float* __restrict__ w,
    const float* __restrict__ b, unsigned short* __restrict__ out) {
    __shared__ float wt[9 * 64];
    __shared__ float bt[64];
    int tid = threadIdx.x;
    for (int i = tid; i < 576; i += 256) {
        int c = i & 63, tap = i >> 6;
        wt[tap * 64 + c] = w[c * 9 + tap];
    }
    if (tid < 64) bt[tid] = b[tid];
    __syncthreads();
    int wi = tid >> 6, c = tid & 63;
    int pix0 = blockIdx.x * 64 + wi * 16;          // first pixel of this wave
    int wcol0 = pix0 & 255, hrow = (pix0 >> 8) & 255, n = pix0 >> 16;
    const float* xb = x + ((size_t)n << 16);
    float acc[16];
    float bb = bt[c];
    #pragma unroll
    for (int p = 0; p < 16; p++) acc[p] = bb;
    #pragma unroll
    for (int dy = 0; dy < 3; dy++) {
        int hy = hrow + dy - 1;
        if (hy < 0 || hy > 255) continue;          // wave-uniform
        const float* rp = xb + (hy << 8) + wcol0;
        float row[18];
        #pragma unroll
        for (int j = 0; j < 18; j++) {
            int gw = wcol0 - 1 + j;
            row[j] = (gw >= 0 && gw < 256) ? rp[j - 1] : 0.f;
        }
        #pragma unroll
        for (int dx = 0; dx < 3; dx++) {
            float wv = wt[(dy * 3 + dx) * 64 + c];
            #pragma unroll
            for (int p = 0; p < 16; p++) acc[p] += row[p + dx] * wv;
        }
    }
    size_t ob = ((size_t)pix0 << 6) + c;
    #pragma unroll
    for (int p = 0; p < 16; p++)
        out[ob + ((size_t)p << 6)] = f2bf(fmaxf(acc[p], 0.f));
}

// ---- conv3x3 2->64 + bias + relu, fp32 [pix][2] in, bf16 NHWC out -----------
__global__ __launch_bounds__(256) void conv_2to64(
    const float* __restrict__ hin, const float* __restrict__ w,
    const float* __restrict__ b, unsigned short* __restrict__ out) {
    __shared__ float wt[18 * 64];
    __shared__ float bt[64];
    int tid = threadIdx.x;
    for (int i = tid; i < 1152; i += 256) {
        int c = i & 63, tc = i >> 6;     // tc = tap*2 + ci
        int tap = tc >> 1, ci = tc & 1;
        wt[tc * 64 + c] = w[(c * 2 + ci) * 9 + tap];
    }
    if (tid < 64) bt[tid] = b[tid];
    __syncthreads();
    int wi = tid >> 6, c = tid & 63;
    int pix0 = blockIdx.x * 64 + wi * 16;
    int wcol0 = pix0 & 255, hrow = (pix0 >> 8) & 255, n = pix0 >> 16;
    const float* hb = hin + ((size_t)n << 17);
    float acc[16];
    float bb = bt[c];
    #pragma unroll
    for (int p = 0; p < 16; p++) acc[p] = bb;
    #pragma unroll
    for (int dy = 0; dy < 3; dy++) {
        int hy = hrow + dy - 1;
        if (hy < 0 || hy > 255) continue;          // wave-uniform
        const float* rp = hb + (((hy << 8) + wcol0) << 1);
        float rx[18], ry[18];
        #pragma unroll
        for (int j = 0; j < 18; j++) {
            int gw = wcol0 - 1 + j;
            bool ok = (gw >= 0 && gw < 256);
            float2 vv = ok ? *(const float2*)(rp + ((j - 1) << 1)) : float2{0.f, 0.f};
            rx[j] = vv.x; ry[j] = vv.y;
        }
        #pragma unroll
        for (int dx = 0; dx < 3; dx++) {
            int tap = dy * 3 + dx;
            float w0 = wt[(tap * 2 + 0) * 64 + c];
            float w1 = wt[(tap * 2 + 1) * 64 + c];
            #pragma unroll
            for (int p = 0; p < 16; p++)
                acc[p] += rx[p + dx] * w0 + ry[p + dx] * w1;
        }
    }
    size_t ob = ((size_t)pix0 << 6) + c;
    #pragma unroll
    for (int p = 0; p < 16; p++)
        out[ob + ((size_t)p << 6)] = f2bf(fmaxf(acc[p], 0.f));
}

// ---- conv3x3 64->NG*16 + bias + relu via MFMA (implicit GEMM) ---------------
// 512 threads = 8 waves; wave w: row = w&3 (full 64-px row, 4 m-tiles),
// g-half = w>>2 (NG/2 output groups).
template <int NG>
__global__ __launch_bounds__(512, 4) void conv_mfma(
    const unsigned short* __restrict__ hin, const unsigned short* __restrict__ bp,
    const float* __restrict__ bias, unsigned short* __restrict__ hout) {
    constexpr int GH = NG / 2;
    __shared__ __align__(16) unsigned short tile[6 * 66 * 72];
    int blk = blockIdx.x;
    int n = blk >> 8;
    int rem = blk & 255;
    int h0 = (rem >> 2) * 4;
    int w0 = (rem & 3) * 64;
    int tid = threadIdx.x;
    const unsigned short* hb = hin + ((size_t)n << 22);
    for (int c = tid; c < 6 * 66 * 8; c += 512) {
        int ch8 = c & 7;
        int cc = (c >> 3) % 66;
        int rr = (c >> 3) / 66;
        int gh = h0 - 1 + rr, gw = w0 - 1 + cc;
        uint4 v = {0u, 0u, 0u, 0u};
        if (gh >= 0 && gh < 256 && gw >= 0 && gw < 256)
            v = *(const uint4*)(hb + (((gh << 8) + gw) << 6) + ch8 * 8);
        *(uint4*)(tile + (rr * 66 + cc) * 72 + ch8 * 8) = v;
    }
    __syncthreads();
    int lane = tid & 63, w = tid >> 6;
    int row = w & 3, ghalf = w >> 2;
    int nl = lane & 15, quad = lane >> 4;
    floatx4 acc[4][GH];
    floatx4 zero = {0.f, 0.f, 0.f, 0.f};
    #pragma unroll
    for (int mi = 0; mi < 4; mi++)
        #pragma unroll
        for (int g = 0; g < GH; g++) acc[mi][g] = zero;
    #pragma unroll
    for (int t = 0; t < 18; t++) {
        const int tap = t >> 1, hf = t & 1;
        const int dy = tap / 3, dx = tap % 3;
        short8 A[4];
        #pragma unroll
        for (int mi = 0; mi < 4; mi++)
            A[mi] = *(const short8*)(tile + ((row + dy) * 66 + mi * 16 + nl + dx) * 72 + hf * 32 + quad * 8);
        #pragma unroll
        for (int g = 0; g < GH; g++) {
            short8 B = *(const short8*)(bp + ((((ghalf * GH + g) * 18 + t) << 6) + lane) * 8);
            #pragma unroll
            for (int mi = 0; mi < 4; mi++)
                acc[mi][g] = __builtin_amdgcn_mfma_f32_16x16x32_bf16(A[mi], B, acc[mi][g], 0, 0, 0);
        }
    }
    size_t obase = ((size_t)((n * 256 + h0 + row)) << 8) + w0;
    #pragma unroll
    for (int g = 0; g < GH; g++) {
        int gg = ghalf * GH + g;
        float bb = bias[gg * 16 + nl];
        #pragma unroll
        for (int mi = 0; mi < 4; mi++) {
            #pragma unroll
            for (int r = 0; r < 4; r++) {
                int pc = mi * 16 + quad * 4 + r;
                float v = fmaxf(acc[mi][g][r] + bb, 0.f);
                hout[(obase + pc) * (NG * 16) + gg * 16 + nl] = f2bf(v);
            }
        }
    }
}

// ---- conv3x3 64->81 (pad 96) + bias + softmax(81) + 9x9 adaptive filter -----
// 512 threads; wave w: row = w&3, g-half = w>>2 (3 of 6 groups). Logits -> LDS
// (bf16, stride 104); epilogue: 2 threads per pixel (taps 0-40 / 41-80), exp
// without max-sub (logits bounded ~|4|), partials combined via LDS.
__global__ __launch_bounds__(512, 4) void conv_softmax_apply(
    const unsigned short* __restrict__ h2b, const unsigned short* __restrict__ bp,
    const float* __restrict__ bias, const float* __restrict__ x,
    float* __restrict__ hout, int head) {
    __shared__ __align__(16) unsigned short tile[6 * 66 * 72];  // reused for logits (256*104)
    __shared__ __align__(16) float xt[12 * 72];
    __shared__ float2 pp[512];
    int blk = blockIdx.x;
    int n = blk >> 8;
    int rem = blk & 255;
    int h0 = (rem >> 2) * 4;
    int w0 = (rem & 3) * 64;
    int tid = threadIdx.x;
    const unsigned short* hb = h2b + ((size_t)n << 22);
    for (int c = tid; c < 6 * 66 * 8; c += 512) {
        int ch8 = c & 7;
        int cc = (c >> 3) % 66;
        int rr = (c >> 3) / 66;
        int gh = h0 - 1 + rr, gw = w0 - 1 + cc;
        uint4 v = {0u, 0u, 0u, 0u};
        if (gh >= 0 && gh < 256 && gw >= 0 && gw < 256)
            v = *(const uint4*)(hb + (((gh << 8) + gw) << 6) + ch8 * 8);
        *(uint4*)(tile + (rr * 66 + cc) * 72 + ch8 * 8) = v;
    }
    const float* xb = x + ((size_t)n << 16);
    for (int c = tid; c < 12 * 72; c += 512) {
        int cc = c % 72, rr = c / 72;
        int gh = h0 - 4 + rr, gw = w0 - 4 + cc;
        xt[c] = (gh >= 0 && gh < 256 && gw >= 0 && gw < 256) ? xb[(gh << 8) + gw] : 0.f;
    }
    __syncthreads();
    int lane = tid & 63, w = tid >> 6;
    int row = w & 3, ghalf = w >> 2;
    int nl = lane & 15, quad = lane >> 4;
    floatx4 acc[4][3];
    floatx4 zero = {0.f, 0.f, 0.f, 0.f};
    #pragma unroll
    for (int mi = 0; mi < 4; mi++)
        #pragma unroll
        for (int g = 0; g < 3; g++) acc[mi][g] = zero;
    #pragma unroll
    for (int t = 0; t < 18; t++) {
        const int tap = t >> 1, hf = t & 1;
        const int dy = tap / 3, dx = tap % 3;
        short8 A[4];
        #pragma unroll
        for (int mi = 0; mi < 4; mi++)
            A[mi] = *(const short8*)(tile + ((row + dy) * 66 + mi * 16 + nl + dx) * 72 + hf * 32 + quad * 8);
        #pragma unroll
        for (int g = 0; g < 3; g++) {
            short8 B = *(const short8*)(bp + ((((ghalf * 3 + g) * 18 + t) << 6) + lane) * 8);
            #pragma unroll
            for (int mi = 0; mi < 4; mi++)
                acc[mi][g] = __builtin_amdgcn_mfma_f32_16x16x32_bf16(A[mi], B, acc[mi][g], 0, 0, 0);
        }
    }
    __syncthreads();   // all waves done reading tile
    // logits (bias added) -> LDS [pixel][channel], bf16, stride 104
    #pragma unroll
    for (int g = 0; g < 3; g++) {
        int ch = (ghalf * 3 + g) * 16 + nl;
        float bb = (ch < 81) ? bias[ch] : 0.f;
        #pragma unroll
        for (int mi = 0; mi < 4; mi++) {
            #pragma unroll
            for (int r = 0; r < 4; r++) {
                int pl = row * 64 + mi * 16 + quad * 4 + r;   // pixel-local 0..255
                tile[pl * 104 + ch] = f2bf(acc[mi][g][r] + bb);
            }
        }
    }
    __syncthreads();
    // epilogue: 2 threads per pixel; h=0 -> taps 0..40, h=1 -> taps 41..80
    int h = tid >> 8, pl = tid & 255;
    int r0 = pl >> 6, c0 = pl & 63;
    const unsigned short* lgp = tile + pl * 104;
    float sum = 0.f, dot = 0.f;
    if (h == 0) {
        short8 lg[6];
        #pragma unroll
        for (int jj = 0; jj < 6; jj++) lg[jj] = *(const short8*)(lgp + jj * 8);
        #pragma unroll
        for (int ch = 0; ch < 41; ch++) {
            float v = bf2f((unsigned short)lg[ch >> 3][ch & 7]);
            float e = __expf(v);
            sum += e;
            dot += e * xt[(r0 + ch / 9) * 72 + c0 + (ch % 9)];
        }
    } else {
        short8 lg[6];
        #pragma unroll
        for (int jj = 0; jj < 6; jj++) lg[jj] = *(const short8*)(lgp + (jj + 5) * 8);
        #pragma unroll
        for (int ch = 41; ch < 81; ch++) {
            float v = bf2f((unsigned short)lg[(ch >> 3) - 5][ch & 7]);
            float e = __expf(v);
            sum += e;
            dot += e * xt[(r0 + ch / 9) * 72 + c0 + (ch % 9)];
        }
    }
    pp[tid] = float2{sum, dot};
    __syncthreads();
    if (tid < 256) {
        float2 a = pp[tid], bq = pp[tid + 256];
        size_t gp = ((size_t)((n * 256 + h0 + r0)) << 8) + w0 + c0;
        hout[gp * 2 + head] = (a.y + bq.y) / (a.x + bq.x);
    }
}

// ---- conv3x3 64->1 + bias via MFMA tile (B group padded 1->16, ch0 valid) ---
__global__ __launch_bounds__(512, 4) void conv_64to1_mfma(
    const unsigned short* __restrict__ h2, const unsigned short* __restrict__ bp,
    const float* __restrict__ b, float* __restrict__ out) {
    __shared__ __align__(16) unsigned short tile[6 * 66 * 72];
    int blk = blockIdx.x;
    int n = blk >> 8;
    int rem = blk & 255;
    int h0 = (rem >> 2) * 4;
    int w0 = (rem & 3) * 64;
    int tid = threadIdx.x;
    const unsigned short* hb = h2 + ((size_t)n << 22);
    for (int c = tid; c < 6 * 66 * 8; c += 512) {
        int ch8 = c & 7;
        int cc = (c >> 3) % 66;
        int rr = (c >> 3) / 66;
        int gh = h0 - 1 + rr, gw = w0 - 1 + cc;
        uint4 v = {0u, 0u, 0u, 0u};
        if (gh >= 0 && gh < 256 && gw >= 0 && gw < 256)
            v = *(const uint4*)(hb + (((gh << 8) + gw) << 6) + ch8 * 8);
        *(uint4*)(tile + (rr * 66 + cc) * 72 + ch8 * 8) = v;
    }
    __syncthreads();
    int lane = tid & 63, w = tid >> 6;
    int row = w & 3, mh = w >> 2;        // this wave: m-tiles {2mh, 2mh+1}
    int nl = lane & 15, quad = lane >> 4;
    floatx4 acc[2];
    floatx4 zero = {0.f, 0.f, 0.f, 0.f};
    acc[0] = zero; acc[1] = zero;
    #pragma unroll
    for (int t = 0; t < 18; t++) {
        const int tap = t >> 1, hf = t & 1;
        const int dy = tap / 3, dx = tap % 3;
        short8 B = *(const short8*)(bp + ((t << 6) + lane) * 8);
        #pragma unroll
        for (int im = 0; im < 2; im++) {
            int mi = mh * 2 + im;
            short8 A = *(const short8*)(tile + ((row + dy) * 66 + mi * 16 + nl + dx) * 72 + hf * 32 + quad * 8);
            acc[im] = __builtin_amdgcn_mfma_f32_16x16x32_bf16(A, B, acc[im], 0, 0, 0);
        }
    }
    if (nl == 0) {
        float b0 = b[0];
        size_t obase = ((size_t)((n * 256 + h0 + row)) << 8) + w0;
        #pragma unroll
        for (int im = 0; im < 2; im++) {
            int mi = mh * 2 + im;
            #pragma unroll
            for (int r = 0; r < 4; r++)
                out[obase + mi * 16 + quad * 4 + r] = acc[im][r] + b0;
        }
    }
}

extern "C" void kernel_launch(void* const* d_in, const int* in_sizes, int n_in,
                              void* d_out, int out_size, void* d_ws, size_t ws_size,
                              hipStream_t stream) {
    const float* x     = (const float*)d_in[0];
    const float* g     = (const float*)d_in[1];
    const float* fx_w1 = (const float*)d_in[2];
    const float* fx_b1 = (const float*)d_in[3];
    const float* fx_w2 = (const float*)d_in[4];
    const float* fx_b2 = (const float*)d_in[5];
    const float* fx_w3 = (const float*)d_in[6];
    const float* fx_b3 = (const float*)d_in[7];
    const float* fg_w1 = (const float*)d_in[8];
    const float* fg_b1 = (const float*)d_in[9];
    const float* fg_w2 = (const float*)d_in[10];
    const float* fg_b2 = (const float*)d_in[11];
    const float* fg_w3 = (const float*)d_in[12];
    const float* fg_b3 = (const float*)d_in[13];
    const float* c1_w  = (const float*)d_in[14];
    const float* c1_b  = (const float*)d_in[15];
    const float* c2_w  = (const float*)d_in[16];
    const float* c2_b  = (const float*)d_in[17];
    const float* c3_w  = (const float*)d_in[18];
    const float* c3_b  = (const float*)d_in[19];
    float* out = (float*)d_out;

    // ---- adaptive workspace layout ------------------------------------------
    const size_t packElems = 230400;   // 6 packs, bf16 elements
    const size_t fixedB = (size_t)P_TOT * 2 * sizeof(float) + packElems * 2 + 256;
    int c = 16;
    while (c > 1 && fixedB + (size_t)c * P_IMG * 256 > ws_size) c >>= 1;
    size_t pcElems = (size_t)c * P_IMG * 64;   // bf16 elements per chunk buffer

    unsigned short* h1 = (unsigned short*)d_ws;
    unsigned short* h2 = h1 + pcElems;
    float* hin = (float*)(h2 + pcElems);
    unsigned short* bp0 = (unsigned short*)(hin + (size_t)P_TOT * 2);
    unsigned short* bp_w2x = bp0;
    unsigned short* bp_w3x = bp0 + 36864;
    unsigned short* bp_w2g = bp0 + 92160;
    unsigned short* bp_w3g = bp0 + 129024;
    unsigned short* bp_c2  = bp0 + 184320;
    unsigned short* bp_c3  = bp0 + 221184;

    dim3 blk(256);
    dim3 blk512(512);
    repack_w<<<144, blk, 0, stream>>>(fx_w2, bp_w2x, 4, 64);
    repack_w<<<216, blk, 0, stream>>>(fx_w3, bp_w3x, 6, 81);
    repack_w<<<144, blk, 0, stream>>>(fg_w2, bp_w2g, 4, 64);
    repack_w<<<216, blk, 0, stream>>>(fg_w3, bp_w3g, 6, 81);
    repack_w<<<144, blk, 0, stream>>>(c2_w,  bp_c2,  4, 64);
    repack_w<<<36,  blk, 0, stream>>>(c3_w,  bp_c3,  1, 1);

    const int nchunk = 16 / c;
    // heads x and g -> hin
    for (int ck = 0; ck < nchunk; ck++) {
        size_t po = (size_t)ck * c * P_IMG;       // pixel offset of chunk
        conv_1to64<<<c * P_IMG / 64, blk, 0, stream>>>(x + po, fx_w1, fx_b1, h1);
        conv_mfma<4><<<c * 256, blk512, 0, stream>>>(h1, bp_w2x, fx_b2, h2);
        conv_softmax_apply<<<c * 256, blk512, 0, stream>>>(h2, bp_w3x, fx_b3, x + po, hin + po * 2, 0);
    }
    for (int ck = 0; ck < nchunk; ck++) {
        size_t po = (size_t)ck * c * P_IMG;
        conv_1to64<<<c * P_IMG / 64, blk, 0, stream>>>(g + po, fg_w1, fg_b1, h1);
        conv_mfma<4><<<c * 256, blk512, 0, stream>>>(h1, bp_w2g, fg_b2, h2);
        conv_softmax_apply<<<c * 256, blk512, 0, stream>>>(h2, bp_w3g, fg_b3, g + po, hin + po * 2, 1);
    }
    // fusion head
    for (int ck = 0; ck < nchunk; ck++) {
        size_t po = (size_t)ck * c * P_IMG;
        conv_2to64<<<c * P_IMG / 64, blk, 0, stream>>>(hin + po * 2, c1_w, c1_b, h1);
        conv_mfma<4><<<c * 256, blk512, 0, stream>>>(h1, bp_c2, c2_b, h2);
        conv_64to1_mfma<<<c * 256, blk512, 0, stream>>>(h2, bp_c3, c3_b, out + po);
    }
}